// Round 1
// baseline (76.544 us; speedup 1.0000x reference)
//
#include <hip/hip_runtime.h>

// B=8, N=512, D=64, E=32
// ws layout: src = ws[0 .. B*N*E), dst = ws[B*N*E .. 2*B*N*E)   (2*524288 floats = 1 MB)

// Kernel 1: src/dst projections (x @ We halves), fold be into src, init out = br.
// Grid 1024 blocks x 256 threads; block = 4 rows x 64 (proj,e) lanes.
// Wave = one row, all 64 (proj,e) -> x-row loads are wave-uniform (SMEM-friendly).
__global__ __launch_bounds__(256) void proj_kernel(
    const float* __restrict__ x, const float* __restrict__ We,
    const float* __restrict__ be, const float* __restrict__ br,
    float* __restrict__ out, float* __restrict__ ws)
{
    const int tid  = threadIdx.x;
    const int pe   = tid & 63;          // (proj, e)
    const int rloc = tid >> 6;          // 0..3
    const int row  = blockIdx.x * 4 + rloc;   // flat (b*512 + i), 0..4095
    const int proj = pe >> 5;           // 0 = src, 1 = dst
    const int e    = pe & 31;

    const float* __restrict__ xrow = x + (size_t)row * 64;
    const float* __restrict__ wcol = We + proj * (64 * 32) + e;

    float acc = 0.0f;
    #pragma unroll
    for (int d = 0; d < 64; ++d)
        acc = fmaf(xrow[d], wcol[d * 32], acc);

    if (proj == 0) acc += be[e];

    ws[(size_t)proj * (4096 * 32) + (size_t)row * 32 + e] = acc;

    // init output with br (harness poisons d_out before every call)
    const int gid = blockIdx.x * 256 + tid;
    if (gid < 4096) out[gid] = br[0];
}

// Kernel 2: delta[b,j] += sum_{i in tile, e} relu(src[b,i,e] + dst[b,j,e]) * Wr[i*32+e]
// Grid (itile=32, jtile=2, b=8) = 512 blocks x 256 threads. lane = j -> src/Wr wave-uniform.
__global__ __launch_bounds__(256) void edge_kernel(
    const float* __restrict__ ws, const float* __restrict__ Wr,
    float* __restrict__ out)
{
    const float* __restrict__ src = ws;
    const float* __restrict__ dst = ws + 4096 * 32;

    const int b  = blockIdx.z;
    const int j  = blockIdx.y * 256 + threadIdx.x;   // 0..511
    const int i0 = blockIdx.x * 16;

    // dst[b, j, 0..31] into registers (8 x float4)
    float d[32];
    const float4* __restrict__ dp =
        (const float4*)(dst + ((size_t)(b * 512 + j)) * 32);
    #pragma unroll
    for (int k = 0; k < 8; ++k) ((float4*)d)[k] = dp[k];

    float acc0 = 0.0f, acc1 = 0.0f;

    #pragma unroll 4
    for (int ii = 0; ii < 16; ++ii) {
        const int i = i0 + ii;
        const float* __restrict__ srow = src + ((size_t)(b * 512 + i)) * 32;
        const float* __restrict__ wrow = Wr + (size_t)i * 32;
        #pragma unroll
        for (int e = 0; e < 32; e += 2) {
            float t0 = fmaxf(srow[e]     + d[e],     0.0f);
            float t1 = fmaxf(srow[e + 1] + d[e + 1], 0.0f);
            acc0 = fmaf(t0, wrow[e],     acc0);
            acc1 = fmaf(t1, wrow[e + 1], acc1);
        }
    }

    atomicAdd(&out[b * 512 + j], acc0 + acc1);
}

extern "C" void kernel_launch(void* const* d_in, const int* in_sizes, int n_in,
                              void* d_out, int out_size, void* d_ws, size_t ws_size,
                              hipStream_t stream) {
    const float* x  = (const float*)d_in[0];   // (8,512,64)
    const float* We = (const float*)d_in[1];   // (128,32)
    const float* be = (const float*)d_in[2];   // (32,)
    const float* Wr = (const float*)d_in[3];   // (16384,1)
    const float* br = (const float*)d_in[4];   // (1,)
    float* out = (float*)d_out;                // (8,512,1) = 4096 floats
    float* ws  = (float*)d_ws;                 // >= 1 MB needed

    proj_kernel<<<1024, 256, 0, stream>>>(x, We, be, br, out, ws);
    edge_kernel<<<dim3(32, 2, 8), 256, 0, stream>>>(ws, Wr, out);
}

// Round 2
// 73.311 us; speedup vs baseline: 1.0441x; 1.0441x over previous
//
#include <hip/hip_runtime.h>

// B=8, N=512, D=64, E=32
// ws layout: src = ws[0 .. 4096*32), dst = ws[4096*32 .. 2*4096*32)  (1 MB total)
#define BNE (4096 * 32)

// Kernel 1: src/dst projections. One wave per row (64-thread blocks) so the
// x-row pointer depends only on blockIdx -> provably uniform -> s_load path.
// lane = (proj, e): proj = lane>>5 (0=src,1=dst), e = lane&31.
__global__ __launch_bounds__(64) void proj_kernel(
    const float* __restrict__ x, const float* __restrict__ We,
    const float* __restrict__ be, const float* __restrict__ br,
    float* __restrict__ out, float* __restrict__ ws)
{
    const int lane = threadIdx.x;          // 0..63
    const int row  = blockIdx.x;           // 0..4095 = b*512 + i  (uniform)
    const int proj = lane >> 5;
    const int e    = lane & 31;

    const float* __restrict__ xrow = x + (size_t)row * 64;        // uniform
    const float* __restrict__ wcol = We + proj * (64 * 32) + e;   // lane-coalesced

    float acc = 0.0f;
    #pragma unroll
    for (int d = 0; d < 64; ++d)
        acc = fmaf(xrow[d], wcol[d * 32], acc);

    if (proj == 0) acc += be[e];           // fold bias into src

    ws[(size_t)proj * BNE + (size_t)row * 32 + e] = acc;

    // init out = br (harness poisons d_out before every call)
    if (blockIdx.x < 64) out[blockIdx.x * 64 + lane] = br[0];
}

// Kernel 2: delta[b,j] += sum_{i in tile, e} relu(src[b,i,e]+dst[b,j,e]) * Wr[i*32+e]
// Each thread owns TWO j's (j, j+256) sharing the wave-uniform (src,Wr) scalars:
// halves uniform-load traffic and gives 4 independent FMA chains.
__global__ __launch_bounds__(256) void edge_kernel(
    const float* __restrict__ ws, const float* __restrict__ Wr,
    float* __restrict__ out)
{
    const float* __restrict__ src = ws;
    const float* __restrict__ dst = ws + BNE;

    const int b  = blockIdx.z;
    const int j0 = threadIdx.x;            // 0..255
    const int j1 = threadIdx.x + 256;      // 256..511
    const int i0 = blockIdx.x * 8;

    float d0[32], d1[32];
    const float4* __restrict__ dp0 = (const float4*)(dst + ((size_t)(b * 512 + j0)) * 32);
    const float4* __restrict__ dp1 = (const float4*)(dst + ((size_t)(b * 512 + j1)) * 32);
    #pragma unroll
    for (int k = 0; k < 8; ++k) {
        ((float4*)d0)[k] = dp0[k];
        ((float4*)d1)[k] = dp1[k];
    }

    float a00 = 0.f, a01 = 0.f, a10 = 0.f, a11 = 0.f;

    #pragma unroll 2
    for (int ii = 0; ii < 8; ++ii) {
        const int i = i0 + ii;
        const float* __restrict__ srow = src + ((size_t)(b * 512 + i)) * 32;  // uniform
        const float* __restrict__ wrow = Wr + (size_t)i * 32;                 // uniform
        #pragma unroll
        for (int e = 0; e < 32; e += 2) {
            const float s0 = srow[e],  s1 = srow[e + 1];
            const float w0 = wrow[e],  w1 = wrow[e + 1];
            float t00 = fmaxf(s0 + d0[e],     0.f);
            float t01 = fmaxf(s1 + d0[e + 1], 0.f);
            float t10 = fmaxf(s0 + d1[e],     0.f);
            float t11 = fmaxf(s1 + d1[e + 1], 0.f);
            a00 = fmaf(t00, w0, a00);
            a01 = fmaf(t01, w1, a01);
            a10 = fmaf(t10, w0, a10);
            a11 = fmaf(t11, w1, a11);
        }
    }

    atomicAdd(&out[b * 512 + j0], a00 + a01);
    atomicAdd(&out[b * 512 + j1], a10 + a11);
}

extern "C" void kernel_launch(void* const* d_in, const int* in_sizes, int n_in,
                              void* d_out, int out_size, void* d_ws, size_t ws_size,
                              hipStream_t stream) {
    const float* x  = (const float*)d_in[0];   // (8,512,64)
    const float* We = (const float*)d_in[1];   // (128,32)
    const float* be = (const float*)d_in[2];   // (32,)
    const float* Wr = (const float*)d_in[3];   // (16384,1)
    const float* br = (const float*)d_in[4];   // (1,)
    float* out = (float*)d_out;                // (8,512,1) = 4096 floats
    float* ws  = (float*)d_ws;

    proj_kernel<<<4096, 64, 0, stream>>>(x, We, be, br, out, ws);
    edge_kernel<<<dim3(64, 1, 8), 256, 0, stream>>>(ws, Wr, out);
}